// Round 1
// baseline (110.346 us; speedup 1.0000x reference)
//
#include <hip/hip_runtime.h>
#include <hip/hip_bf16.h>

// ---------------------------------------------------------------------------
// Metric_Loss: two fused (X X^T/128 -> exp(1+.) -> row-sum) passes + pair combine.
// B=8192, E=128, P=4096.  Output: scalar f32 = metric_tt + metric_st.
//
// ws layout:
//   [0, 2MB)        Xt bf16   [8192][128]
//   [2MB, 4MB)      Xm bf16   [8192][128]  (mixed: even rows text, odd rows shape[r>>1])
//   [4MB, 4MB+64KB) R f32     [2][8192]    row sums of exp(1+D)
// ---------------------------------------------------------------------------

#define B_ROWS 8192
#define E_COLS 128
#define P_PAIRS 4096

using short8 = __attribute__((ext_vector_type(8))) short;
using f32x4  = __attribute__((ext_vector_type(4))) float;

__device__ __forceinline__ unsigned short f2bf(float f) {
    unsigned u = __builtin_bit_cast(unsigned, f);
    unsigned r = (u + 0x7fffu + ((u >> 16) & 1u)) >> 16;   // RNE
    return (unsigned short)r;
}

// --------------------------- conversion kernel -----------------------------
__global__ void convert_kernel(const float* __restrict__ text,
                               const float* __restrict__ shape,
                               unsigned short* __restrict__ Xt,
                               unsigned short* __restrict__ Xm) {
    int idx = blockIdx.x * blockDim.x + threadIdx.x;     // one float4 per thread
    int e = idx * 4;
    if (e >= B_ROWS * E_COLS) return;
    float4 t = *(const float4*)(text + e);
    ushort4 tb;
    tb.x = f2bf(t.x); tb.y = f2bf(t.y); tb.z = f2bf(t.z); tb.w = f2bf(t.w);
    *(ushort4*)(Xt + e) = tb;
    int row = e >> 7;
    if (row & 1) {
        int col = e & 127;
        float4 s = *(const float4*)(shape + (row >> 1) * E_COLS + col);
        ushort4 sb;
        sb.x = f2bf(s.x); sb.y = f2bf(s.y); sb.z = f2bf(s.z); sb.w = f2bf(s.w);
        *(ushort4*)(Xm + e) = sb;
    } else {
        *(ushort4*)(Xm + e) = tb;
    }
}

// --------------------------- fused GEMM + rowsum ---------------------------
// Tile 128x128, K=128 single pass. 256 threads = 4 waves (2x2 of 64x64).
// LDS tiles are linear; bank-conflict-free reads via XOR swizzle applied to
// BOTH the global source address (staging) and the ds_read address.
__device__ __forceinline__ int swz(int row, int cb) {
    return (row << 8) + (cb ^ ((row & 7) << 4));
}

__launch_bounds__(256)
__global__ void gemm_rowsum_kernel(const unsigned short* __restrict__ Xt,
                                   const unsigned short* __restrict__ Xm,
                                   float* __restrict__ R) {
    const int bm = blockIdx.x, bn = blockIdx.y, l = blockIdx.z;
    const unsigned short* X = l ? Xm : Xt;

    __shared__ unsigned short As[128 * 128];
    __shared__ unsigned short Bs[128 * 128];
    const int tid = threadIdx.x;

    const char* gA = (const char*)(X + bm * 128 * E_COLS);
    const char* gB = (const char*)(X + bn * 128 * E_COLS);
    char* lA = (char*)As;
    char* lB = (char*)Bs;

    // Stage 32KB each (contiguous in global since tile spans full K=128 row).
    // LDS dest must be linear (wave-uniform base + lane*16); apply the swizzle
    // on the global SOURCE so swizzled ds_reads return the right data.
#pragma unroll
    for (int it = 0; it < 8; ++it) {
        int L   = it * 4096 + tid * 16;          // linear LDS byte offset
        int row = L >> 8;
        int cb  = L & 255;
        int src = (row << 8) + (cb ^ ((row & 7) << 4));
        __builtin_amdgcn_global_load_lds(
            (const __attribute__((address_space(1))) void*)(gA + src),
            (__attribute__((address_space(3))) void*)(lA + L), 16, 0, 0);
        __builtin_amdgcn_global_load_lds(
            (const __attribute__((address_space(1))) void*)(gB + src),
            (__attribute__((address_space(3))) void*)(lB + L), 16, 0, 0);
    }
    __syncthreads();

    const int lane = tid & 63;
    const int w = tid >> 6;
    const int wr = w >> 1, wc = w & 1;
    const int rA0 = wr * 64 + (lane & 15);
    const int rB0 = wc * 64 + (lane & 15);
    const int kb = (lane >> 4) * 16;             // byte offset of this lane's k-slice

    f32x4 acc[4][4] = {};
#pragma unroll
    for (int kk = 0; kk < 4; ++kk) {
        short8 af[4], bf[4];
        int cb = kk * 64 + kb;
#pragma unroll
        for (int m = 0; m < 4; ++m)
            af[m] = *(const short8*)(lA + swz(rA0 + m * 16, cb));
#pragma unroll
        for (int n = 0; n < 4; ++n)
            bf[n] = *(const short8*)(lB + swz(rB0 + n * 16, cb));
#pragma unroll
        for (int m = 0; m < 4; ++m)
#pragma unroll
            for (int n = 0; n < 4; ++n)
                acc[m][n] = __builtin_amdgcn_mfma_f32_16x16x32_bf16(
                    af[m], bf[n], acc[m][n], 0, 0, 0);
    }

    // Epilogue: exp(1 + D/128), reduce over this tile's columns per row,
    // atomicAdd into global row sums.
    const float inv128 = 0.0078125f;
    const int rowBase = bm * 128 + wr * 64;
#pragma unroll
    for (int m = 0; m < 4; ++m) {
#pragma unroll
        for (int j = 0; j < 4; ++j) {
            float s = 0.f;
#pragma unroll
            for (int n = 0; n < 4; ++n)
                s += __expf(1.0f + acc[m][n][j] * inv128);
            // lanes sharing (lane>>4) hold the same row, 16 distinct columns
#pragma unroll
            for (int sh = 1; sh < 16; sh <<= 1)
                s += __shfl_xor(s, sh, 64);
            if ((lane & 15) == 0) {
                int grow = rowBase + m * 16 + (lane >> 4) * 4 + j;
                atomicAdd(&R[l * B_ROWS + grow], s);
            }
        }
    }
}

// --------------------------- finalize --------------------------------------
__global__ void finalize_kernel(const float* __restrict__ text,
                                const float* __restrict__ shape,
                                const float* __restrict__ R,
                                float* __restrict__ out) {
    const int tid = threadIdx.x;
    const int lane = tid & 63;
    const int w = tid >> 6;
    const int waveGlobal = blockIdx.x * 4 + w;   // 1024 waves total
    const float inv128 = 0.0078125f;
    float accum = 0.f;

    for (int task = waveGlobal; task < 2 * P_PAIRS; task += 1024) {
        int l = task >> 12;
        int p = task & (P_PAIRS - 1);
        const float* a = text + (2 * p) * E_COLS;                       // even row: always text
        const float* b = l ? (shape + p * E_COLS) : (text + (2 * p + 1) * E_COLS);
        float2 av = *(const float2*)(a + lane * 2);
        float2 bv = *(const float2*)(b + lane * 2);
        float dii = av.x * av.x + av.y * av.y;
        float djj = bv.x * bv.x + bv.y * bv.y;
        float dij = av.x * bv.x + av.y * bv.y;
#pragma unroll
        for (int sh = 1; sh < 64; sh <<= 1) {
            dii += __shfl_xor(dii, sh, 64);
            djj += __shfl_xor(djj, sh, 64);
            dij += __shfl_xor(dij, sh, 64);
        }
        if (lane == 0) {
            float Dii = dii * inv128, Djj = djj * inv128, Dij = dij * inv128;
            float S = R[l * B_ROWS + 2 * p] + R[l * B_ROWS + 2 * p + 1]
                    - (__expf(1.f + Dii) + 2.f * __expf(1.f + Dij) + __expf(1.f + Djj));
            float J = __logf(S) - Dij;
            accum += 0.5f * J * J * (1.0f / (float)P_PAIRS);
        }
    }

    __shared__ float red[4];
    if (lane == 0) red[w] = accum;
    __syncthreads();
    if (tid == 0) {
        atomicAdd(out, red[0] + red[1] + red[2] + red[3]);
    }
}

// --------------------------- launch ----------------------------------------
extern "C" void kernel_launch(void* const* d_in, const int* in_sizes, int n_in,
                              void* d_out, int out_size, void* d_ws, size_t ws_size,
                              hipStream_t stream) {
    const float* text  = (const float*)d_in[0];
    const float* shape = (const float*)d_in[1];
    float* out = (float*)d_out;
    char* ws = (char*)d_ws;

    unsigned short* Xt = (unsigned short*)ws;
    unsigned short* Xm = (unsigned short*)(ws + 2u * 1024u * 1024u);
    float* R = (float*)(ws + 4u * 1024u * 1024u);

    hipMemsetAsync(R, 0, 2 * B_ROWS * sizeof(float), stream);
    hipMemsetAsync(out, 0, sizeof(float), stream);

    convert_kernel<<<(B_ROWS * E_COLS / 4 + 255) / 256, 256, 0, stream>>>(
        text, shape, Xt, Xm);

    dim3 grid(B_ROWS / 128, B_ROWS / 128, 2);
    gemm_rowsum_kernel<<<grid, 256, 0, stream>>>(Xt, Xm, R);

    finalize_kernel<<<256, 256, 0, stream>>>(text, shape, R, out);
}

// Round 2
// 50.339 us; speedup vs baseline: 2.1921x; 2.1921x over previous
//
#include <hip/hip_runtime.h>
#include <hip/hip_bf16.h>

// ---------------------------------------------------------------------------
// Metric_Loss: two fused (X X^T/128 -> exp(1+.) -> row-sum) passes + pair combine.
// B=8192, E=128, P=4096.  Output: scalar f32 = metric_tt + metric_st.
//
// Round 2: exploit E-symmetry (only tiles bm<=bn via balanced wrap mapping),
// strip-persistent A fragments in registers, register row-sum accumulation,
// exp2-only epilogue (inputs pre-scaled by sqrt(log2e/128)).
//
// ws layout:
//   [0, 2MB)        Xt bf16   [8192][128]   scaled by sqrt(log2e/128)
//   [2MB, 4MB)      Xm bf16   [8192][128]   (mixed: even=text, odd=shape[r>>1])
//   [4MB, 4MB+64KB) R f32     [2][8192]     row sums of exp(1+D)
// ---------------------------------------------------------------------------

#define B_ROWS 8192
#define E_COLS 128
#define P_PAIRS 4096

using short8 = __attribute__((ext_vector_type(8))) short;
using f32x4  = __attribute__((ext_vector_type(4))) float;

// sqrt(log2(e)/128): MFMA then yields acc = D*log2(e); exp(1+D) = e * exp2(acc)
#define BF_SCALE 0.106164482742544f
#define EULER    2.718281828459045f

__device__ __forceinline__ unsigned short f2bf(float f) {
    unsigned u = __builtin_bit_cast(unsigned, f);
    unsigned r = (u + 0x7fffu + ((u >> 16) & 1u)) >> 16;   // RNE
    return (unsigned short)r;
}

// --------------------------- conversion kernel -----------------------------
__global__ void convert_kernel(const float* __restrict__ text,
                               const float* __restrict__ shape,
                               unsigned short* __restrict__ Xt,
                               unsigned short* __restrict__ Xm,
                               float* __restrict__ R,
                               float* __restrict__ out) {
    int idx = blockIdx.x * blockDim.x + threadIdx.x;     // one float4 per thread
    // zero R (2*8192 f32 = 4096 float4) and out
    if (idx < 4096) {
        float4 z; z.x = z.y = z.z = z.w = 0.f;
        ((float4*)R)[idx] = z;
    }
    if (idx == 0) *out = 0.f;
    int e = idx * 4;
    if (e >= B_ROWS * E_COLS) return;
    float4 t = *(const float4*)(text + e);
    ushort4 tb;
    tb.x = f2bf(t.x * BF_SCALE); tb.y = f2bf(t.y * BF_SCALE);
    tb.z = f2bf(t.z * BF_SCALE); tb.w = f2bf(t.w * BF_SCALE);
    *(ushort4*)(Xt + e) = tb;
    int row = e >> 7;
    if (row & 1) {
        int col = e & 127;
        float4 s = *(const float4*)(shape + (row >> 1) * E_COLS + col);
        ushort4 sb;
        sb.x = f2bf(s.x * BF_SCALE); sb.y = f2bf(s.y * BF_SCALE);
        sb.z = f2bf(s.z * BF_SCALE); sb.w = f2bf(s.w * BF_SCALE);
        *(ushort4*)(Xm + e) = sb;
    } else {
        *(ushort4*)(Xm + e) = tb;
    }
}

// --------------------------- fused GEMM + rowsum ---------------------------
// Block = (strip bm, split h, layer l). Strip bm owns rows [bm*128, bm*128+128).
// Tile loop over distances t = h, h+4, ..., each tile (bm, bn=(bm+t)&63).
// t in {1..31}: each unordered pair once; t==32 gated to bm<32; t==0 diagonal.
// Row sums accumulate in registers; col sums (t>=1) shuffled + atomicAdd'd to
// the partner strip's rows (E symmetric). A-tile staged once, frags hoisted.
__device__ __forceinline__ int swz(int row, int cb) {
    return (row << 8) + (cb ^ ((row & 7) << 4));
}

__launch_bounds__(256, 2)
__global__ void gemm_rowsum_kernel(const unsigned short* __restrict__ Xt,
                                   const unsigned short* __restrict__ Xm,
                                   float* __restrict__ R) {
    const int bm = blockIdx.x, h = blockIdx.y, l = blockIdx.z;
    const unsigned short* X = l ? Xm : Xt;

    __shared__ unsigned short As[128 * 128];
    __shared__ unsigned short Bs[128 * 128];
    const int tid = threadIdx.x;
    char* lA = (char*)As;
    char* lB = (char*)Bs;

    // ---- stage A strip (pre-swizzled global source, linear LDS dest) ----
    {
        const char* gA = (const char*)(X + bm * 128 * E_COLS);
#pragma unroll
        for (int it = 0; it < 8; ++it) {
            int L   = it * 4096 + tid * 16;
            int row = L >> 8;
            int cb  = L & 255;
            int src = (row << 8) + (cb ^ ((row & 7) << 4));
            __builtin_amdgcn_global_load_lds(
                (const __attribute__((address_space(1))) void*)(gA + src),
                (__attribute__((address_space(3))) void*)(lA + L), 16, 0, 0);
        }
    }
    __syncthreads();

    const int lane = tid & 63;
    const int w = tid >> 6;
    const int wr = w >> 1, wc = w & 1;
    const int rA0 = wr * 64 + (lane & 15);
    const int rB0 = wc * 64 + (lane & 15);
    const int kb = (lane >> 4) * 16;             // byte offset of lane's k-slice

    // ---- hoist A fragments for the whole strip ----
    short8 afr[4][4];                            // [kk][m]
#pragma unroll
    for (int kk = 0; kk < 4; ++kk)
#pragma unroll
        for (int m = 0; m < 4; ++m)
            afr[kk][m] = *(const short8*)(lA + swz(rA0 + m * 16, kk * 64 + kb));

    float s_r[4][4] = {{0.f}};                   // persistent row partials [m][j]

    for (int t = h; t <= 32; t += 4) {
        if (t == 32 && bm >= 32) break;          // (bm,bm+32) owned by bm<32
        const int bn = (bm + t) & 63;
        const bool diag = (t == 0);

        if (!diag) {
            __syncthreads();                     // prior tile's Bs reads done
            const char* gB = (const char*)(X + bn * 128 * E_COLS);
#pragma unroll
            for (int it = 0; it < 8; ++it) {
                int L   = it * 4096 + tid * 16;
                int row = L >> 8;
                int cb  = L & 255;
                int src = (row << 8) + (cb ^ ((row & 7) << 4));
                __builtin_amdgcn_global_load_lds(
                    (const __attribute__((address_space(1))) void*)(gB + src),
                    (__attribute__((address_space(3))) void*)(lB + L), 16, 0, 0);
            }
            __syncthreads();
        }
        const char* lsrc = diag ? lA : lB;

        f32x4 acc[4][4] = {};
#pragma unroll
        for (int kk = 0; kk < 4; ++kk) {
            short8 bfr[4];
            int cb = kk * 64 + kb;
#pragma unroll
            for (int n = 0; n < 4; ++n)
                bfr[n] = *(const short8*)(lsrc + swz(rB0 + n * 16, cb));
#pragma unroll
            for (int m = 0; m < 4; ++m)
#pragma unroll
                for (int n = 0; n < 4; ++n)
                    acc[m][n] = __builtin_amdgcn_mfma_f32_16x16x32_bf16(
                        afr[kk][m], bfr[n], acc[m][n], 0, 0, 0);
        }

        // ---- epilogue: e2 = exp2(D*log2e); rows -> regs, cols -> atomics ----
        float s_c[4] = {0.f, 0.f, 0.f, 0.f};
#pragma unroll
        for (int m = 0; m < 4; ++m)
#pragma unroll
            for (int n = 0; n < 4; ++n)
#pragma unroll
                for (int j = 0; j < 4; ++j) {
                    float e2 = __builtin_amdgcn_exp2f(acc[m][n][j]);
                    s_r[m][j] += e2;
                    s_c[n] += e2;
                }
        if (!diag) {
#pragma unroll
            for (int n = 0; n < 4; ++n) {
                float v = s_c[n];
                v += __shfl_xor(v, 16, 64);
                v += __shfl_xor(v, 32, 64);
                if ((lane >> 4) == 0) {
                    int gcol = bn * 128 + wc * 64 + n * 16 + (lane & 15);
                    atomicAdd(&R[l * B_ROWS + gcol], EULER * v);
                }
            }
        }
    }

    // ---- final row reduction (once per block) ----
#pragma unroll
    for (int m = 0; m < 4; ++m)
#pragma unroll
        for (int j = 0; j < 4; ++j) {
            float v = s_r[m][j];
            v += __shfl_xor(v, 1, 64);
            v += __shfl_xor(v, 2, 64);
            v += __shfl_xor(v, 4, 64);
            v += __shfl_xor(v, 8, 64);
            if ((lane & 15) == 0) {
                int grow = bm * 128 + wr * 64 + m * 16 + (lane >> 4) * 4 + j;
                atomicAdd(&R[l * B_ROWS + grow], EULER * v);
            }
        }
}

// --------------------------- finalize --------------------------------------
__global__ void finalize_kernel(const float* __restrict__ text,
                                const float* __restrict__ shape,
                                const float* __restrict__ R,
                                float* __restrict__ out) {
    const int tid = threadIdx.x;
    const int lane = tid & 63;
    const int w = tid >> 6;
    const int waveGlobal = blockIdx.x * 4 + w;   // 1024 waves total
    const float inv128 = 0.0078125f;
    float accum = 0.f;

    for (int task = waveGlobal; task < 2 * P_PAIRS; task += 1024) {
        int l = task >> 12;
        int p = task & (P_PAIRS - 1);
        const float* a = text + (2 * p) * E_COLS;                       // even row: always text
        const float* b = l ? (shape + p * E_COLS) : (text + (2 * p + 1) * E_COLS);
        float2 av = *(const float2*)(a + lane * 2);
        float2 bv = *(const float2*)(b + lane * 2);
        float dii = av.x * av.x + av.y * av.y;
        float djj = bv.x * bv.x + bv.y * bv.y;
        float dij = av.x * bv.x + av.y * bv.y;
#pragma unroll
        for (int sh = 1; sh < 64; sh <<= 1) {
            dii += __shfl_xor(dii, sh, 64);
            djj += __shfl_xor(djj, sh, 64);
            dij += __shfl_xor(dij, sh, 64);
        }
        if (lane == 0) {
            float Dii = dii * inv128, Djj = djj * inv128, Dij = dij * inv128;
            float S = R[l * B_ROWS + 2 * p] + R[l * B_ROWS + 2 * p + 1]
                    - (__expf(1.f + Dii) + 2.f * __expf(1.f + Dij) + __expf(1.f + Djj));
            float J = __logf(S) - Dij;
            accum += 0.5f * J * J * (1.0f / (float)P_PAIRS);
        }
    }

    __shared__ float red[4];
    if (lane == 0) red[w] = accum;
    __syncthreads();
    if (tid == 0) {
        atomicAdd(out, red[0] + red[1] + red[2] + red[3]);
    }
}

// --------------------------- launch ----------------------------------------
extern "C" void kernel_launch(void* const* d_in, const int* in_sizes, int n_in,
                              void* d_out, int out_size, void* d_ws, size_t ws_size,
                              hipStream_t stream) {
    const float* text  = (const float*)d_in[0];
    const float* shape = (const float*)d_in[1];
    float* out = (float*)d_out;
    char* ws = (char*)d_ws;

    unsigned short* Xt = (unsigned short*)ws;
    unsigned short* Xm = (unsigned short*)(ws + 2u * 1024u * 1024u);
    float* R = (float*)(ws + 4u * 1024u * 1024u);

    convert_kernel<<<(B_ROWS * E_COLS / 4 + 255) / 256, 256, 0, stream>>>(
        text, shape, Xt, Xm, R, out);

    dim3 grid(B_ROWS / 128, 4, 2);               // 64 strips x 4 splits x 2 layers
    gemm_rowsum_kernel<<<grid, 256, 0, stream>>>(Xt, Xm, R);

    finalize_kernel<<<256, 256, 0, stream>>>(text, shape, R, out);
}

// Round 3
// 49.504 us; speedup vs baseline: 2.2290x; 1.0169x over previous
//
#include <hip/hip_runtime.h>
#include <hip/hip_bf16.h>

// ---------------------------------------------------------------------------
// Metric_Loss: two fused (X X^T/128 -> exp(1+.) -> row-sum) passes + pair combine.
// B=8192, E=128, P=4096.  Output: scalar f32 = metric_tt + metric_st.
//
// Round 3: double-buffered B staging with counted vmcnt (T3/T4 2-phase):
// A-frags hoisted to regs, then As is reused as the 2nd B buffer. Prefetch of
// tile t+4 stays in flight across compute+epilogue of tile t (never vmcnt(0)
// in steady state). Everything else as round 2 (symmetry, exp2 pre-scale).
//
// ws layout:
//   [0, 2MB)        Xt bf16   [8192][128]   scaled by sqrt(log2e/128)
//   [2MB, 4MB)      Xm bf16   [8192][128]   (mixed: even=text, odd=shape[r>>1])
//   [4MB, 4MB+64KB) R f32     [2][8192]     row sums of exp(1+D)
// ---------------------------------------------------------------------------

#define B_ROWS 8192
#define E_COLS 128
#define P_PAIRS 4096

using short8 = __attribute__((ext_vector_type(8))) short;
using f32x4  = __attribute__((ext_vector_type(4))) float;

// sqrt(log2(e)/128): MFMA then yields acc = D*log2(e); exp(1+D) = e * exp2(acc)
#define BF_SCALE 0.106164482742544f
#define EULER    2.718281828459045f

__device__ __forceinline__ unsigned short f2bf(float f) {
    unsigned u = __builtin_bit_cast(unsigned, f);
    unsigned r = (u + 0x7fffu + ((u >> 16) & 1u)) >> 16;   // RNE
    return (unsigned short)r;
}

// --------------------------- conversion kernel -----------------------------
__global__ void convert_kernel(const float* __restrict__ text,
                               const float* __restrict__ shape,
                               unsigned short* __restrict__ Xt,
                               unsigned short* __restrict__ Xm,
                               float* __restrict__ R,
                               float* __restrict__ out) {
    int idx = blockIdx.x * blockDim.x + threadIdx.x;     // one float4 per thread
    // zero R (2*8192 f32 = 4096 float4) and out
    if (idx < 4096) {
        float4 z; z.x = z.y = z.z = z.w = 0.f;
        ((float4*)R)[idx] = z;
    }
    if (idx == 0) *out = 0.f;
    int e = idx * 4;
    if (e >= B_ROWS * E_COLS) return;
    float4 t = *(const float4*)(text + e);
    ushort4 tb;
    tb.x = f2bf(t.x * BF_SCALE); tb.y = f2bf(t.y * BF_SCALE);
    tb.z = f2bf(t.z * BF_SCALE); tb.w = f2bf(t.w * BF_SCALE);
    *(ushort4*)(Xt + e) = tb;
    int row = e >> 7;
    if (row & 1) {
        int col = e & 127;
        float4 s = *(const float4*)(shape + (row >> 1) * E_COLS + col);
        ushort4 sb;
        sb.x = f2bf(s.x * BF_SCALE); sb.y = f2bf(s.y * BF_SCALE);
        sb.z = f2bf(s.z * BF_SCALE); sb.w = f2bf(s.w * BF_SCALE);
        *(ushort4*)(Xm + e) = sb;
    } else {
        *(ushort4*)(Xm + e) = tb;
    }
}

// --------------------------- fused GEMM + rowsum ---------------------------
__device__ __forceinline__ int swz(int row, int cb) {
    return (row << 8) + (cb ^ ((row & 7) << 4));
}

// Stage one 128x128 bf16 tile (32KB): linear LDS dest, pre-swizzled global src.
__device__ __forceinline__ void stage_tile(const char* gsrc, char* ldst, int tid) {
#pragma unroll
    for (int it = 0; it < 8; ++it) {
        int L   = it * 4096 + tid * 16;
        int row = L >> 8;
        int cb  = L & 255;
        int src = (row << 8) + (cb ^ ((row & 7) << 4));
        __builtin_amdgcn_global_load_lds(
            (const __attribute__((address_space(1))) void*)(gsrc + src),
            (__attribute__((address_space(3))) void*)(ldst + L), 16, 0, 0);
    }
}

// Block = (strip bm, split h, layer l). Strip bm owns rows [bm*128, bm*128+128).
// Distances t = h, h+4, ...; tile (bm, bn=(bm+t)&63). t in {1..31}: each
// unordered pair once; t==32 gated to bm<32; t==0 diagonal (h==0 blocks).
__launch_bounds__(256, 2)
__global__ void gemm_rowsum_kernel(const unsigned short* __restrict__ Xt,
                                   const unsigned short* __restrict__ Xm,
                                   float* __restrict__ R) {
    const int bm = blockIdx.x, h = blockIdx.y, l = blockIdx.z;
    const unsigned short* X = l ? Xm : Xt;

    __shared__ __align__(16) unsigned short As[128 * 128];
    __shared__ __align__(16) unsigned short Bs[128 * 128];
    const int tid = threadIdx.x;
    char* lA = (char*)As;
    char* lB = (char*)Bs;
    const char* gX = (const char*)X;

    // ---- stage A strip, full drain (prologue only) ----
    stage_tile(gX + bm * 32768, lA, tid);
    __syncthreads();

    const int t0   = (h == 0) ? 4 : h;
    const int tmax = (h == 0) ? (bm < 32 ? 32 : 28) : (h + 28);

    // ---- prefetch first B tile; stays in flight across afr hoist + diag ----
    stage_tile(gX + ((bm + t0) & 63) * 32768, lB, tid);

    const int lane = tid & 63;
    const int w = tid >> 6;
    const int wr = w >> 1, wc = w & 1;
    const int rA0 = wr * 64 + (lane & 15);
    const int rB0 = wc * 64 + (lane & 15);
    const int kb = (lane >> 4) * 16;             // byte offset of lane's k-slice

    // ---- hoist A fragments for the whole strip ----
    short8 afr[4][4];                            // [kk][m]
#pragma unroll
    for (int kk = 0; kk < 4; ++kk)
#pragma unroll
        for (int m = 0; m < 4; ++m)
            afr[kk][m] = *(const short8*)(lA + swz(rA0 + m * 16, kk * 64 + kb));

    float s_r[4][4] = {{0.f}};                   // persistent row partials [m][j]

    auto compute_tile = [&](const char* lsrc, f32x4 (&acc)[4][4]) {
#pragma unroll
        for (int kk = 0; kk < 4; ++kk) {
            short8 bfr[4];
            int cb = kk * 64 + kb;
#pragma unroll
            for (int n = 0; n < 4; ++n)
                bfr[n] = *(const short8*)(lsrc + swz(rB0 + n * 16, cb));
#pragma unroll
            for (int m = 0; m < 4; ++m)
#pragma unroll
                for (int n = 0; n < 4; ++n)
                    acc[m][n] = __builtin_amdgcn_mfma_f32_16x16x32_bf16(
                        afr[kk][m], bfr[n], acc[m][n], 0, 0, 0);
        }
    };

    // ---- diagonal tile (h==0): compute straight from As while B(t0) flies ----
    if (h == 0) {
        f32x4 acc[4][4] = {};
        compute_tile(lA, acc);
#pragma unroll
        for (int m = 0; m < 4; ++m)
#pragma unroll
            for (int n = 0; n < 4; ++n)
#pragma unroll
                for (int j = 0; j < 4; ++j)
                    s_r[m][j] += __builtin_amdgcn_exp2f(acc[m][n][j]);
    }

    // ---- all As reads done everywhere before As becomes a B buffer ----
    asm volatile("s_waitcnt lgkmcnt(0)" ::: "memory");
    __builtin_amdgcn_s_barrier();

    // ---- 2-phase pipelined loop over off-diagonal tiles ----
    int cur = 0;                                 // 0 -> lB, 1 -> lA
    for (int t = t0; t <= tmax; t += 4) {
        const bool hasnext = (t + 4 <= tmax);
        if (hasnext)
            stage_tile(gX + ((bm + t + 4) & 63) * 32768, cur ? lB : lA, tid);

        if (hasnext) { asm volatile("s_waitcnt vmcnt(8)" ::: "memory"); }
        else         { asm volatile("s_waitcnt vmcnt(0)" ::: "memory"); }
        __builtin_amdgcn_s_barrier();            // cur buffer staged (all waves)

        const char* lsrc = cur ? lA : lB;
        f32x4 acc[4][4] = {};
        compute_tile(lsrc, acc);

        asm volatile("s_waitcnt lgkmcnt(0)" ::: "memory");
        __builtin_amdgcn_s_barrier();            // cur reads done -> overwritable

        // ---- epilogue: e2 = exp2(D*log2e); rows -> regs, cols -> atomics ----
        const int bn = (bm + t) & 63;
        float s_c[4] = {0.f, 0.f, 0.f, 0.f};
#pragma unroll
        for (int m = 0; m < 4; ++m)
#pragma unroll
            for (int n = 0; n < 4; ++n)
#pragma unroll
                for (int j = 0; j < 4; ++j) {
                    float e2 = __builtin_amdgcn_exp2f(acc[m][n][j]);
                    s_r[m][j] += e2;
                    s_c[n] += e2;
                }
#pragma unroll
        for (int n = 0; n < 4; ++n) {
            float v = s_c[n];
            v += __shfl_xor(v, 16, 64);
            v += __shfl_xor(v, 32, 64);
            if ((lane >> 4) == 0) {
                int gcol = bn * 128 + wc * 64 + n * 16 + (lane & 15);
                atomicAdd(&R[l * B_ROWS + gcol], EULER * v);
            }
        }
        cur ^= 1;
    }

    // ---- final row reduction (once per block) ----
#pragma unroll
    for (int m = 0; m < 4; ++m)
#pragma unroll
        for (int j = 0; j < 4; ++j) {
            float v = s_r[m][j];
            v += __shfl_xor(v, 1, 64);
            v += __shfl_xor(v, 2, 64);
            v += __shfl_xor(v, 4, 64);
            v += __shfl_xor(v, 8, 64);
            if ((lane & 15) == 0) {
                int grow = bm * 128 + wr * 64 + m * 16 + (lane >> 4) * 4 + j;
                atomicAdd(&R[l * B_ROWS + grow], EULER * v);
            }
        }
}

// --------------------------- finalize --------------------------------------
__global__ void finalize_kernel(const float* __restrict__ text,
                                const float* __restrict__ shape,
                                const float* __restrict__ R,
                                float* __restrict__ out) {
    const int tid = threadIdx.x;
    const int lane = tid & 63;
    const int w = tid >> 6;
    const int waveGlobal = blockIdx.x * 4 + w;   // 1024 waves total
    const float inv128 = 0.0078125f;
    float accum = 0.f;

    for (int task = waveGlobal; task < 2 * P_PAIRS; task += 1024) {
        int l = task >> 12;
        int p = task & (P_PAIRS - 1);
        const float* a = text + (2 * p) * E_COLS;                       // even row: always text
        const float* b = l ? (shape + p * E_COLS) : (text + (2 * p + 1) * E_COLS);
        float2 av = *(const float2*)(a + lane * 2);
        float2 bv = *(const float2*)(b + lane * 2);
        float dii = av.x * av.x + av.y * av.y;
        float djj = bv.x * bv.x + bv.y * bv.y;
        float dij = av.x * bv.x + av.y * bv.y;
#pragma unroll
        for (int sh = 1; sh < 64; sh <<= 1) {
            dii += __shfl_xor(dii, sh, 64);
            djj += __shfl_xor(djj, sh, 64);
            dij += __shfl_xor(dij, sh, 64);
        }
        if (lane == 0) {
            float Dii = dii * inv128, Djj = djj * inv128, Dij = dij * inv128;
            float S = R[l * B_ROWS + 2 * p] + R[l * B_ROWS + 2 * p + 1]
                    - (__expf(1.f + Dii) + 2.f * __expf(1.f + Dij) + __expf(1.f + Djj));
            float J = __logf(S) - Dij;
            accum += 0.5f * J * J * (1.0f / (float)P_PAIRS);
        }
    }

    __shared__ float red[4];
    if (lane == 0) red[w] = accum;
    __syncthreads();
    if (tid == 0) {
        atomicAdd(out, red[0] + red[1] + red[2] + red[3]);
    }
}

// --------------------------- launch ----------------------------------------
extern "C" void kernel_launch(void* const* d_in, const int* in_sizes, int n_in,
                              void* d_out, int out_size, void* d_ws, size_t ws_size,
                              hipStream_t stream) {
    const float* text  = (const float*)d_in[0];
    const float* shape = (const float*)d_in[1];
    float* out = (float*)d_out;
    char* ws = (char*)d_ws;

    unsigned short* Xt = (unsigned short*)ws;
    unsigned short* Xm = (unsigned short*)(ws + 2u * 1024u * 1024u);
    float* R = (float*)(ws + 4u * 1024u * 1024u);

    convert_kernel<<<(B_ROWS * E_COLS / 4 + 255) / 256, 256, 0, stream>>>(
        text, shape, Xt, Xm, R, out);

    dim3 grid(B_ROWS / 128, 4, 2);               // 64 strips x 4 splits x 2 layers
    gemm_rowsum_kernel<<<grid, 256, 0, stream>>>(Xt, Xm, R);

    finalize_kernel<<<256, 256, 0, stream>>>(text, shape, R, out);
}